// Round 4
// baseline (640.647 us; speedup 1.0000x reference)
//
#include <hip/hip_runtime.h>

// ---------------------------------------------------------------------------
// MultiHeadAttention_60000693125780 — round 4
//  * convs on mfma_f32_32x32x16_bf16 (2495 TF ceiling vs 2075; half the
//    instruction count per K-chunk)  — scores/pv stay on verified 16x16
//  * single merged prep kernel; Sp zero folded into softmax; pv scatters
//    directly into padded-NHWC Sp (k_prep_sp + Oa roundtrip deleted)
//  * 6 launches total
// Layouts: Qh/Ql,Kh/Kl [nn][dd][t] bf16 hi/lo; Vt [nn][t][dd] bf16;
//          Ph [nn][q][k'] bf16; Sp padded NHWC bf16 [4][10][258][512]
// 32x32 MFMA lane maps: A m=lane&31,k=(lane>>5)*8+j; B n=lane&31 same k;
//                       C/D col=lane&31,row=(reg&3)+8*(reg>>2)+4*(lane>>5)
// ---------------------------------------------------------------------------

typedef __attribute__((ext_vector_type(8))) short short8;
typedef __attribute__((ext_vector_type(4))) float f32x4;
typedef __attribute__((ext_vector_type(16))) float f32x16;
typedef __attribute__((ext_vector_type(4))) short short4v;

#define MFMA16(a, b, c) __builtin_amdgcn_mfma_f32_16x16x32_bf16((a), (b), (c), 0, 0, 0)
#define MFMA32(a, b, c) __builtin_amdgcn_mfma_f32_32x32x16_bf16((a), (b), (c), 0, 0, 0)

__device__ __forceinline__ void gl_lds16(const void* g, void* l) {
    __builtin_amdgcn_global_load_lds(
        (const __attribute__((address_space(1))) unsigned int*)g,
        (__attribute__((address_space(3))) unsigned int*)l, 16, 0, 0);
}
__device__ __forceinline__ unsigned short f2bf(float f) {
    unsigned u = __float_as_uint(f);
    return (unsigned short)((u + 0x7fffu + ((u >> 16) & 1u)) >> 16);
}
__device__ __forceinline__ float bf2f(unsigned short h) {
    return __uint_as_float(((unsigned)h) << 16);
}

// ---- merged prep: blocks [0,36864) weights, [36864,102144) inputs ----
__global__ __launch_bounds__(256) void k_prep_all(
        const float* __restrict__ q, const float* __restrict__ k,
        const float* __restrict__ v,
        const float* __restrict__ Wq, const float* __restrict__ Wk,
        const float* __restrict__ Wv, const float* __restrict__ Wo,
        unsigned short* __restrict__ Wqh, unsigned short* __restrict__ Wql,
        unsigned short* __restrict__ Wkh, unsigned short* __restrict__ Wkl,
        unsigned short* __restrict__ Wvh, unsigned short* __restrict__ Woh,
        unsigned short* __restrict__ Xqh, unsigned short* __restrict__ Xql,
        unsigned short* __restrict__ Xkh, unsigned short* __restrict__ Xkl,
        unsigned short* __restrict__ Xvh) {
    int b = blockIdx.x;
    if (b < 36864) {
        int z = b / 9216;
        const float* W = z == 0 ? Wq : z == 1 ? Wk : z == 2 ? Wv : Wo;
        unsigned short* Wh = z == 0 ? Wqh : z == 1 ? Wkh : z == 2 ? Wvh : Woh;
        unsigned short* Wl = z == 0 ? Wql : z == 1 ? Wkl : nullptr;
        unsigned tid = (unsigned)(b % 9216) * 256 + threadIdx.x;   // 512*4608
        unsigned ci  = tid & 511;
        unsigned tap = (tid >> 9) % 9u;
        unsigned co  = tid / 4608u;
        float wv = W[(co * 512 + ci) * 9 + tap];
        unsigned short h = f2bf(wv);
        Wh[tid] = h;
        if (Wl) Wl[tid] = f2bf(wv - bf2f(h));
    } else {
        int bb = b - 36864;
        int z = bb / 21760;
        const float* X = z == 0 ? q : z == 1 ? k : v;
        unsigned short* Xh = z == 0 ? Xqh : z == 1 ? Xkh : Xvh;
        unsigned short* Xl = z == 0 ? Xql : Xkl;
        if (z == 2) Xl = nullptr;
        unsigned o = (unsigned)(bb % 21760) * 256 + threadIdx.x;   // 32*34*10*512
        unsigned ci = o & 511;
        unsigned u  = o >> 9;
        unsigned xx = u % 10u; u /= 10u;
        unsigned yy = u % 34u;
        unsigned n  = u / 34u;
        float val = 0.f;
        if (xx >= 1 && xx <= 8 && yy >= 1 && yy <= 32)
            val = X[(n * 512 + ci) * 256 + (yy - 1) * 8 + (xx - 1)];
        unsigned short h = f2bf(val);
        Xh[o] = h;
        if (Xl) Xl[o] = f2bf(val - bf2f(h));
    }
}

// ---- merged QKV conv, 32x32x16: z=0 Q(split), z=1 K(split), z=2 V(->Vt) ----
__global__ __launch_bounds__(256) void k_conv_qkv_all(
        const unsigned short* __restrict__ Xqh, const unsigned short* __restrict__ Xql,
        const unsigned short* __restrict__ Xkh, const unsigned short* __restrict__ Xkl,
        const unsigned short* __restrict__ Xvh,
        const unsigned short* __restrict__ Wqh_, const unsigned short* __restrict__ Wql_,
        const unsigned short* __restrict__ Wkh_, const unsigned short* __restrict__ Wkl_,
        const unsigned short* __restrict__ Wvh_,
        const float* __restrict__ bq, const float* __restrict__ bk,
        const float* __restrict__ bv,
        unsigned short* __restrict__ Qh, unsigned short* __restrict__ Ql,
        unsigned short* __restrict__ Kh, unsigned short* __restrict__ Kl,
        unsigned short* __restrict__ Vt) {
    __shared__ __align__(16) short Ah[4096], Al[4096], Bh[4096], Bl[4096];
    const int z = blockIdx.z;
    const bool split = (z < 2);
    const unsigned short* Xh = z == 0 ? Xqh : z == 1 ? Xkh : Xvh;
    const unsigned short* Xl = z == 0 ? Xql : Xkl;
    const unsigned short* Wh = z == 0 ? Wqh_ : z == 1 ? Wkh_ : Wvh_;
    const unsigned short* Wl = z == 0 ? Wql_ : Wkl_;
    const float* bias = z == 0 ? bq : z == 1 ? bk : bv;
    unsigned short* Oh = z == 0 ? Qh : Kh;
    unsigned short* Ol = z == 0 ? Ql : Kl;

    const int tid = threadIdx.x;
    const int w = tid >> 6, l = tid & 63;
    const int n   = blockIdx.x >> 1;
    const int p0  = (blockIdx.x & 1) * 128;
    const int co0 = blockIdx.y * 128;

    // staging addresses (source-side XOR swizzle; dest = uniform + lane*16)
    int arow[2], brow[2];
#pragma unroll
    for (int i = 0; i < 2; ++i) {
        int rr = w * 32 + i * 16 + (l >> 2);
        int c  = (l & 3) ^ ((rr >> 1) & 3);
        int px = p0 + rr;
        int y = px >> 3, x = px & 7;
        arow[i] = ((n * 34 + y + 1) * 10 + (x + 1)) * 512 + c * 8;
        brow[i] = (co0 + rr) * 4608 + c * 8;
    }
    const int lds0 = w * 2048, lds1 = w * 2048 + 1024;

    // fragment offsets (shorts): 32x32 A/B frags, b128 each
    int aoff[2][2], boff[2][2];
#pragma unroll
    for (int mt = 0; mt < 2; ++mt) {
        int row = (w & 1) * 64 + mt * 32 + (l & 31);
#pragma unroll
        for (int ks = 0; ks < 2; ++ks) {
            int cc = ks * 2 + (l >> 5);
            aoff[mt][ks] = row * 32 + (cc ^ ((row >> 1) & 3)) * 8;
        }
    }
#pragma unroll
    for (int nt = 0; nt < 2; ++nt) {
        int row = (w >> 1) * 64 + nt * 32 + (l & 31);
#pragma unroll
        for (int ks = 0; ks < 2; ++ks) {
            int cc = ks * 2 + (l >> 5);
            boff[nt][ks] = row * 32 + (cc ^ ((row >> 1) & 3)) * 8;
        }
    }

    f32x16 acc[2][2];
#pragma unroll
    for (int nt = 0; nt < 2; ++nt) {
        float b = bias[co0 + (w >> 1) * 64 + nt * 32 + (l & 31)];
#pragma unroll
        for (int mt = 0; mt < 2; ++mt)
#pragma unroll
            for (int r = 0; r < 16; ++r) acc[mt][nt][r] = b;
    }

    for (int tap = 0; tap < 9; ++tap) {
        const int tapoff = ((tap / 3 - 1) * 10 + (tap % 3 - 1)) * 512;
        const int wb = tap * 512;
        for (int ci0 = 0; ci0 < 512; ci0 += 32) {
            int a0 = arow[0] + tapoff + ci0, a1 = arow[1] + tapoff + ci0;
            int b0 = brow[0] + wb + ci0,     b1 = brow[1] + wb + ci0;
            gl_lds16(Xh + a0, (char*)Ah + lds0);
            gl_lds16(Xh + a1, (char*)Ah + lds1);
            gl_lds16(Wh + b0, (char*)Bh + lds0);
            gl_lds16(Wh + b1, (char*)Bh + lds1);
            if (split) {
                gl_lds16(Xl + a0, (char*)Al + lds0);
                gl_lds16(Xl + a1, (char*)Al + lds1);
                gl_lds16(Wl + b0, (char*)Bl + lds0);
                gl_lds16(Wl + b1, (char*)Bl + lds1);
            }
            __syncthreads();
            short8 ah[2][2], bh[2][2];
#pragma unroll
            for (int mt = 0; mt < 2; ++mt)
#pragma unroll
                for (int ks = 0; ks < 2; ++ks) ah[mt][ks] = *(const short8*)&Ah[aoff[mt][ks]];
#pragma unroll
            for (int nt = 0; nt < 2; ++nt)
#pragma unroll
                for (int ks = 0; ks < 2; ++ks) bh[nt][ks] = *(const short8*)&Bh[boff[nt][ks]];
#pragma unroll
            for (int ks = 0; ks < 2; ++ks)
#pragma unroll
                for (int mt = 0; mt < 2; ++mt)
#pragma unroll
                    for (int nt = 0; nt < 2; ++nt)
                        acc[mt][nt] = MFMA32(ah[mt][ks], bh[nt][ks], acc[mt][nt]);
            if (split) {
                short8 t2[2][2];
#pragma unroll
                for (int mt = 0; mt < 2; ++mt)
#pragma unroll
                    for (int ks = 0; ks < 2; ++ks) t2[mt][ks] = *(const short8*)&Al[aoff[mt][ks]];
#pragma unroll
                for (int ks = 0; ks < 2; ++ks)
#pragma unroll
                    for (int mt = 0; mt < 2; ++mt)
#pragma unroll
                        for (int nt = 0; nt < 2; ++nt)
                            acc[mt][nt] = MFMA32(t2[mt][ks], bh[nt][ks], acc[mt][nt]);
#pragma unroll
                for (int nt = 0; nt < 2; ++nt)
#pragma unroll
                    for (int ks = 0; ks < 2; ++ks) t2[nt][ks] = *(const short8*)&Bl[boff[nt][ks]];
#pragma unroll
                for (int ks = 0; ks < 2; ++ks)
#pragma unroll
                    for (int mt = 0; mt < 2; ++mt)
#pragma unroll
                        for (int nt = 0; nt < 2; ++nt)
                            acc[mt][nt] = MFMA32(ah[mt][ks], t2[nt][ks], acc[mt][nt]);
            }
            __syncthreads();
        }
    }

    const int hh = n >> 2, nl = n & 3;
#pragma unroll
    for (int mt = 0; mt < 2; ++mt) {
        int pxq = p0 + (w & 1) * 64 + mt * 32 + 4 * (l >> 5);
#pragma unroll
        for (int g = 0; g < 4; ++g) {
            int px = pxq + g * 8;
            int y = px >> 3;
            int t0 = hh * 32 + (y & 3) * 8 + (px & 7);
#pragma unroll
            for (int nt = 0; nt < 2; ++nt) {
                int co = co0 + (w >> 1) * 64 + nt * 32 + (l & 31);
                int nn = nl * 8 + (co >> 6);
                int dd = (co & 63) * 8 + (y >> 2);
                if (split) {
                    short4v hv, lv;
#pragma unroll
                    for (int r = 0; r < 4; ++r) {
                        float xv = acc[mt][nt][g * 4 + r];
                        unsigned short hb = f2bf(xv);
                        hv[r] = (short)hb;
                        lv[r] = (short)f2bf(xv - bf2f(hb));
                    }
                    int base = (nn * 512 + dd) * 256 + t0;
                    *(short4v*)&Oh[base] = hv;
                    *(short4v*)&Ol[base] = lv;
                } else {
#pragma unroll
                    for (int r = 0; r < 4; ++r)
                        Vt[(nn * 256 + t0 + r) * 512 + dd] = f2bf(acc[mt][nt][g * 4 + r]);
                }
            }
        }
    }
}

// ---- scores: Sc[nn][q][k'] fp32 via split-bf16 16x16 MFMA (K=256) ----
__global__ __launch_bounds__(256) void k_scores_mfma(
        const unsigned short* __restrict__ Qh, const unsigned short* __restrict__ Ql,
        const unsigned short* __restrict__ Kh, const unsigned short* __restrict__ Kl,
        float* __restrict__ Sc) {
    __shared__ __align__(16) short Ah[4096], Al[4096], Bh[4096], Bl[4096];
    const int tid = threadIdx.x;
    const int w = tid >> 6, l = tid & 63;
    const int q0 = blockIdx.x * 128, k0 = blockIdx.y * 128, nn = blockIdx.z;
    const int lm = l & 15, lq = l >> 4;

    int arow[2], brow[2];
#pragma unroll
    for (int i = 0; i < 2; ++i) {
        int rr = w * 32 + i * 16 + (l >> 2);
        int c  = (l & 3) ^ ((rr >> 1) & 3);
        arow[i] = (nn * 512 + q0 + rr) * 256 + c * 8;
        brow[i] = (nn * 512 + k0 + rr) * 256 + c * 8;
    }
    const int lds0 = w * 2048, lds1 = w * 2048 + 1024;

    int aoff[4], boff[4];
#pragma unroll
    for (int mi = 0; mi < 4; ++mi) {
        int row = (w & 1) * 64 + mi * 16 + lm;
        aoff[mi] = row * 32 + (lq ^ ((row >> 1) & 3)) * 8;
    }
#pragma unroll
    for (int ni = 0; ni < 4; ++ni) {
        int row = (w >> 1) * 64 + ni * 16 + lm;
        boff[ni] = row * 32 + (lq ^ ((row >> 1) & 3)) * 8;
    }

    f32x4 acc[4][4];
#pragma unroll
    for (int mi = 0; mi < 4; ++mi)
#pragma unroll
        for (int ni = 0; ni < 4; ++ni) acc[mi][ni] = (f32x4){0.f, 0.f, 0.f, 0.f};

    for (int t0 = 0; t0 < 256; t0 += 32) {
        gl_lds16(Qh + arow[0] + t0, (char*)Ah + lds0);
        gl_lds16(Qh + arow[1] + t0, (char*)Ah + lds1);
        gl_lds16(Ql + arow[0] + t0, (char*)Al + lds0);
        gl_lds16(Ql + arow[1] + t0, (char*)Al + lds1);
        gl_lds16(Kh + brow[0] + t0, (char*)Bh + lds0);
        gl_lds16(Kh + brow[1] + t0, (char*)Bh + lds1);
        gl_lds16(Kl + brow[0] + t0, (char*)Bl + lds0);
        gl_lds16(Kl + brow[1] + t0, (char*)Bl + lds1);
        __syncthreads();
        short8 ah[4], bh[4];
#pragma unroll
        for (int mi = 0; mi < 4; ++mi) ah[mi] = *(const short8*)&Ah[aoff[mi]];
#pragma unroll
        for (int ni = 0; ni < 4; ++ni) bh[ni] = *(const short8*)&Bh[boff[ni]];
#pragma unroll
        for (int mi = 0; mi < 4; ++mi)
#pragma unroll
            for (int ni = 0; ni < 4; ++ni)
                acc[mi][ni] = MFMA16(ah[mi], bh[ni], acc[mi][ni]);
        {
            short8 alv[4], blv[4];
#pragma unroll
            for (int mi = 0; mi < 4; ++mi) alv[mi] = *(const short8*)&Al[aoff[mi]];
#pragma unroll
            for (int mi = 0; mi < 4; ++mi)
#pragma unroll
                for (int ni = 0; ni < 4; ++ni)
                    acc[mi][ni] = MFMA16(alv[mi], bh[ni], acc[mi][ni]);
#pragma unroll
            for (int ni = 0; ni < 4; ++ni) blv[ni] = *(const short8*)&Bl[boff[ni]];
#pragma unroll
            for (int mi = 0; mi < 4; ++mi)
#pragma unroll
                for (int ni = 0; ni < 4; ++ni)
                    acc[mi][ni] = MFMA16(ah[mi], blv[ni], acc[mi][ni]);
        }
        __syncthreads();
    }

    float* C = Sc + nn * 262144;
#pragma unroll
    for (int mi = 0; mi < 4; ++mi) {
        int qb = q0 + (w & 1) * 64 + lq * 4 + mi * 16;
#pragma unroll
        for (int ni = 0; ni < 4; ++ni) {
            int col = k0 + (w >> 1) * 64 + ni * 16 + lm;
#pragma unroll
            for (int r = 0; r < 4; ++r)
                C[(qb + r) * 512 + col] = acc[mi][ni][r];
        }
    }
}

// ---- softmax rows of 512 (+ zero Sp halo buffer while we're here) ----
__global__ __launch_bounds__(256) void k_softmax(float* __restrict__ Sc,
                                                 unsigned short* __restrict__ Ph,
                                                 unsigned int* __restrict__ Spz) {
    unsigned zi = blockIdx.x * 256 + threadIdx.x;
    if (zi < 2641920u) Spz[zi] = 0u;           // 5,283,840 shorts of Sp
    __shared__ float red[8];
    float* p = Sc + (size_t)blockIdx.x * 512;
    unsigned short* ph = Ph + (size_t)blockIdx.x * 512;
    const int tid = threadIdx.x;
    float x0 = p[tid], x1 = p[tid + 256];
    float m = fmaxf(x0, x1);
#pragma unroll
    for (int off = 32; off; off >>= 1) m = fmaxf(m, __shfl_xor(m, off));
    if ((tid & 63) == 0) red[tid >> 6] = m;
    __syncthreads();
    m = fmaxf(fmaxf(red[0], red[1]), fmaxf(red[2], red[3]));
    float e0 = __expf(x0 - m), e1 = __expf(x1 - m);
    float s = e0 + e1;
#pragma unroll
    for (int off = 32; off; off >>= 1) s += __shfl_xor(s, off);
    if ((tid & 63) == 0) red[4 + (tid >> 6)] = s;
    __syncthreads();
    s = red[4] + red[5] + red[6] + red[7];
    float inv = 1.0f / s;
    float p0 = e0 * inv, p1 = e1 * inv;
    p[tid] = p0;
    p[tid + 256] = p1;
    ph[tid] = f2bf(p0);
    ph[tid + 256] = f2bf(p1);
}

// ---- PV: P @ V, 16x16 bf16 MFMA; epilogue scatters into padded Sp ----
__global__ __launch_bounds__(256) void k_pv_mfma(
        const unsigned short* __restrict__ Ph, const unsigned short* __restrict__ Vt,
        unsigned short* __restrict__ Sp) {
    __shared__ __align__(16) short Ah[4096], Bh[2048];
    const int tid = threadIdx.x;
    const int w = tid >> 6, l = tid & 63;
    const int q0 = blockIdx.x * 128, t0 = blockIdx.y * 64, nn = blockIdx.z;
    const int lm = l & 15, lq = l >> 4;

    int arow[2], brow;
#pragma unroll
    for (int i = 0; i < 2; ++i) {
        int rr = w * 32 + i * 16 + (l >> 2);
        int c  = (l & 3) ^ ((rr >> 1) & 3);
        arow[i] = (nn * 512 + q0 + rr) * 512 + c * 8;
    }
    {
        int rr = w * 16 + (l >> 2);
        int c  = (l & 3) ^ ((rr >> 1) & 3);
        brow = (nn * 256 + t0 + rr) * 512 + c * 8;
    }
    const int ldsA0 = w * 2048, ldsA1 = w * 2048 + 1024, ldsB = w * 1024;

    int aoff[4], boff[2];
#pragma unroll
    for (int mi = 0; mi < 4; ++mi) {
        int row = (w & 1) * 64 + mi * 16 + lm;
        aoff[mi] = row * 32 + (lq ^ ((row >> 1) & 3)) * 8;
    }
#pragma unroll
    for (int ni = 0; ni < 2; ++ni) {
        int row = (w >> 1) * 32 + ni * 16 + lm;
        boff[ni] = row * 32 + (lq ^ ((row >> 1) & 3)) * 8;
    }

    f32x4 acc[4][2];
#pragma unroll
    for (int mi = 0; mi < 4; ++mi)
#pragma unroll
        for (int ni = 0; ni < 2; ++ni) acc[mi][ni] = (f32x4){0.f, 0.f, 0.f, 0.f};

    for (int kc = 0; kc < 512; kc += 32) {
        gl_lds16(Ph + arow[0] + kc, (char*)Ah + ldsA0);
        gl_lds16(Ph + arow[1] + kc, (char*)Ah + ldsA1);
        gl_lds16(Vt + brow + kc, (char*)Bh + ldsB);
        __syncthreads();
        short8 a[4], b[2];
#pragma unroll
        for (int mi = 0; mi < 4; ++mi) a[mi] = *(const short8*)&Ah[aoff[mi]];
#pragma unroll
        for (int ni = 0; ni < 2; ++ni) b[ni] = *(const short8*)&Bh[boff[ni]];
#pragma unroll
        for (int mi = 0; mi < 4; ++mi)
#pragma unroll
            for (int ni = 0; ni < 2; ++ni)
                acc[mi][ni] = MFMA16(a[mi], b[ni], acc[mi][ni]);
        __syncthreads();
    }

    // scatter into Sp[b2][yy][xx][d2]:  (nn,qp,t) -> b2=nn>>3, s2=nn&7,
    //   ww=(qp>>4)*8+((qp>>1)&7), d2=(qp&1)*256+(t&31)*8+(t>>5)
    const int b2 = nn >> 3, s2 = nn & 7;
#pragma unroll
    for (int mi = 0; mi < 4; ++mi) {
        int qb = q0 + (w & 1) * 64 + lq * 4 + mi * 16;
#pragma unroll
        for (int ni = 0; ni < 2; ++ni) {
            int tc = t0 + (w >> 1) * 32 + ni * 16 + lm;
            int d2base = (tc & 31) * 8 + (tc >> 5);
#pragma unroll
            for (int r = 0; r < 4; ++r) {
                int qp = qb + r;
                int ww = (qp >> 4) * 8 + ((qp >> 1) & 7);
                int d2 = (qp & 1) * 256 + d2base;
                Sp[((b2 * 10 + s2 + 1) * 258 + ww + 1) * 512 + d2] =
                    f2bf(acc[mi][ni][r]);
            }
        }
    }
}

// ---- output conv, 32x32x16 bf16, BM=128 BN=64 -> Y NCHW fp32 ----
__global__ __launch_bounds__(256) void k_conv_o_mfma(
        const unsigned short* __restrict__ Sp, const unsigned short* __restrict__ Wh,
        const float* __restrict__ bias, float* __restrict__ Y) {
    __shared__ __align__(16) short Ah[4096], Bh[2048];
    const int tid = threadIdx.x;
    const int w = tid >> 6, l = tid & 63;
    const int n   = blockIdx.x >> 4;
    const int yy  = (blockIdx.x >> 1) & 7;
    const int x0  = (blockIdx.x & 1) * 128;
    const int co0 = blockIdx.y * 64;

    int arow[2], brow;
#pragma unroll
    for (int i = 0; i < 2; ++i) {
        int rr = w * 32 + i * 16 + (l >> 2);
        int c  = (l & 3) ^ ((rr >> 1) & 3);
        arow[i] = ((n * 10 + yy + 1) * 258 + (x0 + rr + 1)) * 512 + c * 8;
    }
    {
        int rr = w * 16 + (l >> 2);
        int c  = (l & 3) ^ ((rr >> 1) & 3);
        brow = (co0 + rr) * 4608 + c * 8;
    }
    const int ldsA0 = w * 2048, ldsA1 = w * 2048 + 1024, ldsB = w * 1024;

    int aoff[2][2], boff[2];
#pragma unroll
    for (int mt = 0; mt < 2; ++mt) {
        int row = (w & 1) * 64 + mt * 32 + (l & 31);
#pragma unroll
        for (int ks = 0; ks < 2; ++ks) {
            int cc = ks * 2 + (l >> 5);
            aoff[mt][ks] = row * 32 + (cc ^ ((row >> 1) & 3)) * 8;
        }
    }
    {
        int row = (w >> 1) * 32 + (l & 31);
#pragma unroll
        for (int ks = 0; ks < 2; ++ks) {
            int cc = ks * 2 + (l >> 5);
            boff[ks] = row * 32 + (cc ^ ((row >> 1) & 3)) * 8;
        }
    }

    f32x16 acc[2];
    {
        float b = bias[co0 + (w >> 1) * 32 + (l & 31)];
#pragma unroll
        for (int mt = 0; mt < 2; ++mt)
#pragma unroll
            for (int r = 0; r < 16; ++r) acc[mt][r] = b;
    }

    for (int tap = 0; tap < 9; ++tap) {
        const int tapoff = ((tap / 3 - 1) * 258 + (tap % 3 - 1)) * 512;
        const int wb = tap * 512;
        for (int ci0 = 0; ci0 < 512; ci0 += 32) {
            gl_lds16(Sp + arow[0] + tapoff + ci0, (char*)Ah + ldsA0);
            gl_lds16(Sp + arow[1] + tapoff + ci0, (char*)Ah + ldsA1);
            gl_lds16(Wh + brow + wb + ci0, (char*)Bh + ldsB);
            __syncthreads();
            short8 a[2][2], b[2];
#pragma unroll
            for (int mt = 0; mt < 2; ++mt)
#pragma unroll
                for (int ks = 0; ks < 2; ++ks) a[mt][ks] = *(const short8*)&Ah[aoff[mt][ks]];
#pragma unroll
            for (int ks = 0; ks < 2; ++ks) b[ks] = *(const short8*)&Bh[boff[ks]];
#pragma unroll
            for (int ks = 0; ks < 2; ++ks)
#pragma unroll
                for (int mt = 0; mt < 2; ++mt)
                    acc[mt] = MFMA32(a[mt][ks], b[ks], acc[mt]);
            __syncthreads();
        }
    }

    const int co = co0 + (w >> 1) * 32 + (l & 31);
#pragma unroll
    for (int mt = 0; mt < 2; ++mt) {
        int pxq = x0 + (w & 1) * 64 + mt * 32 + 4 * (l >> 5);
#pragma unroll
        for (int g = 0; g < 4; ++g) {
            int px = pxq + g * 8;
            f32x4 vv = {acc[mt][g * 4 + 0], acc[mt][g * 4 + 1],
                        acc[mt][g * 4 + 2], acc[mt][g * 4 + 3]};
            *(f32x4*)&Y[n * 1048576 + co * 2048 + yy * 256 + px] = vv;
        }
    }
}

// ---------------------------------------------------------------------------
extern "C" void kernel_launch(void* const* d_in, const int* in_sizes, int n_in,
                              void* d_out, int out_size, void* d_ws, size_t ws_size,
                              hipStream_t stream) {
    const float* q  = (const float*)d_in[0];
    const float* k  = (const float*)d_in[1];
    const float* v  = (const float*)d_in[2];
    const float* Wq = (const float*)d_in[3];
    const float* bq = (const float*)d_in[4];
    const float* Wk = (const float*)d_in[5];
    const float* bk = (const float*)d_in[6];
    const float* Wv = (const float*)d_in[7];
    const float* bv = (const float*)d_in[8];
    const float* Wo = (const float*)d_in[9];
    const float* bo = (const float*)d_in[10];

    // ---- workspace layout (shorts); total 40,697,856 shorts = 81.4 MB ----
    unsigned short* W0  = (unsigned short*)d_ws;
    unsigned short* Wqh = W0;                   // 2359296 each
    unsigned short* Wql = W0 + 2359296;
    unsigned short* Wkh = W0 + 4718592;
    unsigned short* Wkl = W0 + 7077888;
    unsigned short* Wvh = W0 + 9437184;
    unsigned short* Woh = W0 + 11796480;
    unsigned short* Xvh = W0 + 14155776;        // 5570560
    unsigned short* Qh  = W0 + 19726336;        // 4194304 each
    unsigned short* Ql  = W0 + 23920640;
    unsigned short* Kh  = W0 + 28114944;
    unsigned short* Kl  = W0 + 32309248;
    unsigned short* Vt  = W0 + 36503552;
    // reuses (lifetimes): Ph over Wq*/Wk* (dead after conv);
    //                     Sp over Ql+Kh (dead after scores)
    unsigned short* Ph = W0;                    // 8388608 shorts
    unsigned short* Sp = W0 + 23920640;         // 5283840 shorts

    // ---- d_out scratch before final writes ----
    float* y_out = (float*)d_out;               // 4194304 floats (written last)
    float* attn  = y_out + 4194304;             // 8388608 floats (written by scores)
    unsigned short* Xqh = (unsigned short*)d_out;
    unsigned short* Xql = (unsigned short*)attn;
    unsigned short* Xkh = Xql + 5570560;
    unsigned short* Xkl = Xkh + 5570560;

    k_prep_all<<<102144, 256, 0, stream>>>(q, k, v, Wq, Wk, Wv, Wo,
                                           Wqh, Wql, Wkh, Wkl, Wvh, Woh,
                                           Xqh, Xql, Xkh, Xkl, Xvh);
    k_conv_qkv_all<<<dim3(64, 4, 3), 256, 0, stream>>>(
        Xqh, Xql, Xkh, Xkl, Xvh, Wqh, Wql, Wkh, Wkl, Wvh,
        bq, bk, bv, Qh, Ql, Kh, Kl, Vt);
    k_scores_mfma<<<dim3(4, 4, 32), 256, 0, stream>>>(Qh, Ql, Kh, Kl, attn);
    k_softmax<<<16384, 256, 0, stream>>>(attn, Ph, (unsigned int*)Sp);
    k_pv_mfma<<<dim3(4, 4, 32), 256, 0, stream>>>(Ph, Vt, Sp);
    k_conv_o_mfma<<<dim3(64, 8), 256, 0, stream>>>(Sp, Woh, bo, y_out);
}

// Round 5
// 588.217 us; speedup vs baseline: 1.0891x; 1.0891x over previous
//
#include <hip/hip_runtime.h>

// ---------------------------------------------------------------------------
// MultiHeadAttention_60000693125780 — round 5
//  = round 3's proven 16x16 MFMA convs (0 bank conflicts, VGPR 72, 48% MfmaUtil)
//  + round 4's fusion structure (merged prep, softmax zeroes Sp, pv scatters
//    directly into padded-NHWC Sp, 6 launches total).
//  Round 4's 32x32 convs regressed: the ((row>>1)&3) swizzle with only 2
//  chunk variants per half-wave aliases rows 8 apart onto one bank quad
//  (4-way b128 conflicts, 2.36e7 measured) and VGPR 104 cut occupancy.
// Layouts: Qh/Ql,Kh/Kl [nn][dd][t] bf16 hi/lo; Vt [nn][t][dd] bf16;
//          Ph [nn][q][k'] bf16; Sp padded NHWC bf16 [4][10][258][512]
// ---------------------------------------------------------------------------

typedef __attribute__((ext_vector_type(8))) short short8;
typedef __attribute__((ext_vector_type(4))) float f32x4;
typedef __attribute__((ext_vector_type(4))) short short4v;

#define MFMA16(a, b, c) __builtin_amdgcn_mfma_f32_16x16x32_bf16((a), (b), (c), 0, 0, 0)

__device__ __forceinline__ void gl_lds16(const void* g, void* l) {
    __builtin_amdgcn_global_load_lds(
        (const __attribute__((address_space(1))) unsigned int*)g,
        (__attribute__((address_space(3))) unsigned int*)l, 16, 0, 0);
}
__device__ __forceinline__ unsigned short f2bf(float f) {
    unsigned u = __float_as_uint(f);
    return (unsigned short)((u + 0x7fffu + ((u >> 16) & 1u)) >> 16);
}
__device__ __forceinline__ float bf2f(unsigned short h) {
    return __uint_as_float(((unsigned)h) << 16);
}

// ---- merged prep: blocks [0,36864) weights, [36864,102144) inputs ----
__global__ __launch_bounds__(256) void k_prep_all(
        const float* __restrict__ q, const float* __restrict__ k,
        const float* __restrict__ v,
        const float* __restrict__ Wq, const float* __restrict__ Wk,
        const float* __restrict__ Wv, const float* __restrict__ Wo,
        unsigned short* __restrict__ Wqh, unsigned short* __restrict__ Wql,
        unsigned short* __restrict__ Wkh, unsigned short* __restrict__ Wkl,
        unsigned short* __restrict__ Wvh, unsigned short* __restrict__ Woh,
        unsigned short* __restrict__ Xqh, unsigned short* __restrict__ Xql,
        unsigned short* __restrict__ Xkh, unsigned short* __restrict__ Xkl,
        unsigned short* __restrict__ Xvh) {
    int b = blockIdx.x;
    if (b < 36864) {
        int z = b / 9216;
        const float* W = z == 0 ? Wq : z == 1 ? Wk : z == 2 ? Wv : Wo;
        unsigned short* Wh = z == 0 ? Wqh : z == 1 ? Wkh : z == 2 ? Wvh : Woh;
        unsigned short* Wl = z == 0 ? Wql : z == 1 ? Wkl : nullptr;
        unsigned tid = (unsigned)(b % 9216) * 256 + threadIdx.x;   // 512*4608
        unsigned ci  = tid & 511;
        unsigned tap = (tid >> 9) % 9u;
        unsigned co  = tid / 4608u;
        float wv = W[(co * 512 + ci) * 9 + tap];
        unsigned short h = f2bf(wv);
        Wh[tid] = h;
        if (Wl) Wl[tid] = f2bf(wv - bf2f(h));
    } else {
        int bb = b - 36864;
        int z = bb / 21760;
        const float* X = z == 0 ? q : z == 1 ? k : v;
        unsigned short* Xh = z == 0 ? Xqh : z == 1 ? Xkh : Xvh;
        unsigned short* Xl = z == 0 ? Xql : Xkl;
        if (z == 2) Xl = nullptr;
        unsigned o = (unsigned)(bb % 21760) * 256 + threadIdx.x;   // 32*34*10*512
        unsigned ci = o & 511;
        unsigned u  = o >> 9;
        unsigned xx = u % 10u; u /= 10u;
        unsigned yy = u % 34u;
        unsigned n  = u / 34u;
        float val = 0.f;
        if (xx >= 1 && xx <= 8 && yy >= 1 && yy <= 32)
            val = X[(n * 512 + ci) * 256 + (yy - 1) * 8 + (xx - 1)];
        unsigned short h = f2bf(val);
        Xh[o] = h;
        if (Xl) Xl[o] = f2bf(val - bf2f(h));
    }
}

// ---- merged QKV conv (16x16): z=0 Q(split), z=1 K(split), z=2 V(->Vt) ----
__global__ __launch_bounds__(256) void k_conv_qkv_all(
        const unsigned short* __restrict__ Xqh, const unsigned short* __restrict__ Xql,
        const unsigned short* __restrict__ Xkh, const unsigned short* __restrict__ Xkl,
        const unsigned short* __restrict__ Xvh,
        const unsigned short* __restrict__ Wqh_, const unsigned short* __restrict__ Wql_,
        const unsigned short* __restrict__ Wkh_, const unsigned short* __restrict__ Wkl_,
        const unsigned short* __restrict__ Wvh_,
        const float* __restrict__ bq, const float* __restrict__ bk,
        const float* __restrict__ bv,
        unsigned short* __restrict__ Qh, unsigned short* __restrict__ Ql,
        unsigned short* __restrict__ Kh, unsigned short* __restrict__ Kl,
        unsigned short* __restrict__ Vt) {
    __shared__ __align__(16) short Ah[4096], Al[4096], Bh[4096], Bl[4096];
    const int z = blockIdx.z;
    const bool split = (z < 2);
    const unsigned short* Xh = z == 0 ? Xqh : z == 1 ? Xkh : Xvh;
    const unsigned short* Xl = z == 0 ? Xql : Xkl;
    const unsigned short* Wh = z == 0 ? Wqh_ : z == 1 ? Wkh_ : Wvh_;
    const unsigned short* Wl = z == 0 ? Wql_ : Wkl_;
    const float* bias = z == 0 ? bq : z == 1 ? bk : bv;
    unsigned short* Oh = z == 0 ? Qh : Kh;
    unsigned short* Ol = z == 0 ? Ql : Kl;

    const int tid = threadIdx.x;
    const int w = tid >> 6, l = tid & 63;
    const int n   = blockIdx.x >> 1;
    const int p0  = (blockIdx.x & 1) * 128;
    const int co0 = blockIdx.y * 128;
    const int lm = l & 15, lq = l >> 4;

    int arow[2], brow[2];
#pragma unroll
    for (int i = 0; i < 2; ++i) {
        int rr = w * 32 + i * 16 + (l >> 2);
        int c  = (l & 3) ^ ((rr >> 1) & 3);             // XOR bank swizzle
        int px = p0 + rr;
        int y = px >> 3, x = px & 7;
        arow[i] = ((n * 34 + y + 1) * 10 + (x + 1)) * 512 + c * 8;
        brow[i] = (co0 + rr) * 4608 + c * 8;
    }
    const int lds0 = w * 2048, lds1 = w * 2048 + 1024;

    int aoff[4], boff[4];
#pragma unroll
    for (int mi = 0; mi < 4; ++mi) {
        int row = (w & 1) * 64 + mi * 16 + lm;
        aoff[mi] = row * 32 + (lq ^ ((row >> 1) & 3)) * 8;
    }
#pragma unroll
    for (int ni = 0; ni < 4; ++ni) {
        int row = (w >> 1) * 64 + ni * 16 + lm;
        boff[ni] = row * 32 + (lq ^ ((row >> 1) & 3)) * 8;
    }

    f32x4 acc[4][4];
#pragma unroll
    for (int ni = 0; ni < 4; ++ni) {
        float b = bias[co0 + (w >> 1) * 64 + ni * 16 + lm];
#pragma unroll
        for (int mi = 0; mi < 4; ++mi) acc[mi][ni] = (f32x4){b, b, b, b};
    }

    for (int tap = 0; tap < 9; ++tap) {
        const int tapoff = ((tap / 3 - 1) * 10 + (tap % 3 - 1)) * 512;
        const int wb = tap * 512;
        for (int ci0 = 0; ci0 < 512; ci0 += 32) {
            int a0 = arow[0] + tapoff + ci0, a1 = arow[1] + tapoff + ci0;
            int b0 = brow[0] + wb + ci0,     b1 = brow[1] + wb + ci0;
            gl_lds16(Xh + a0, (char*)Ah + lds0);
            gl_lds16(Xh + a1, (char*)Ah + lds1);
            gl_lds16(Wh + b0, (char*)Bh + lds0);
            gl_lds16(Wh + b1, (char*)Bh + lds1);
            if (split) {
                gl_lds16(Xl + a0, (char*)Al + lds0);
                gl_lds16(Xl + a1, (char*)Al + lds1);
                gl_lds16(Wl + b0, (char*)Bl + lds0);
                gl_lds16(Wl + b1, (char*)Bl + lds1);
            }
            __syncthreads();
            short8 ah[4], bh[4];
#pragma unroll
            for (int mi = 0; mi < 4; ++mi) ah[mi] = *(const short8*)&Ah[aoff[mi]];
#pragma unroll
            for (int ni = 0; ni < 4; ++ni) bh[ni] = *(const short8*)&Bh[boff[ni]];
#pragma unroll
            for (int mi = 0; mi < 4; ++mi)
#pragma unroll
                for (int ni = 0; ni < 4; ++ni)
                    acc[mi][ni] = MFMA16(ah[mi], bh[ni], acc[mi][ni]);
            if (split) {
                short8 alv[4], blv[4];
#pragma unroll
                for (int mi = 0; mi < 4; ++mi) alv[mi] = *(const short8*)&Al[aoff[mi]];
#pragma unroll
                for (int mi = 0; mi < 4; ++mi)
#pragma unroll
                    for (int ni = 0; ni < 4; ++ni)
                        acc[mi][ni] = MFMA16(alv[mi], bh[ni], acc[mi][ni]);
#pragma unroll
                for (int ni = 0; ni < 4; ++ni) blv[ni] = *(const short8*)&Bl[boff[ni]];
#pragma unroll
                for (int mi = 0; mi < 4; ++mi)
#pragma unroll
                    for (int ni = 0; ni < 4; ++ni)
                        acc[mi][ni] = MFMA16(ah[mi], blv[ni], acc[mi][ni]);
            }
            __syncthreads();
        }
    }

    const int hh = n >> 2, nl = n & 3;
    const int pxbase = p0 + (w & 1) * 64 + lq * 4;
    const int x0q = pxbase & 7;
#pragma unroll
    for (int mi = 0; mi < 4; ++mi) {
        int px = pxbase + mi * 16;
        int y = px >> 3;
#pragma unroll
        for (int ni = 0; ni < 4; ++ni) {
            int co = co0 + (w >> 1) * 64 + ni * 16 + lm;
            int nn = nl * 8 + (co >> 6);
            int dd = (co & 63) * 8 + (y >> 2);
            int t0 = hh * 32 + (y & 3) * 8 + x0q;
            if (split) {
                short4v hv, lv;
#pragma unroll
                for (int r = 0; r < 4; ++r) {
                    float xv = acc[mi][ni][r];
                    unsigned short hb = f2bf(xv);
                    hv[r] = (short)hb;
                    lv[r] = (short)f2bf(xv - bf2f(hb));
                }
                int base = (nn * 512 + dd) * 256 + t0;
                *(short4v*)&Oh[base] = hv;
                *(short4v*)&Ol[base] = lv;
            } else {
#pragma unroll
                for (int r = 0; r < 4; ++r)
                    Vt[(nn * 256 + t0 + r) * 512 + dd] = f2bf(acc[mi][ni][r]);
            }
        }
    }
}

// ---- scores: Sc[nn][q][k'] fp32 via split-bf16 16x16 MFMA (K=256) ----
__global__ __launch_bounds__(256) void k_scores_mfma(
        const unsigned short* __restrict__ Qh, const unsigned short* __restrict__ Ql,
        const unsigned short* __restrict__ Kh, const unsigned short* __restrict__ Kl,
        float* __restrict__ Sc) {
    __shared__ __align__(16) short Ah[4096], Al[4096], Bh[4096], Bl[4096];
    const int tid = threadIdx.x;
    const int w = tid >> 6, l = tid & 63;
    const int q0 = blockIdx.x * 128, k0 = blockIdx.y * 128, nn = blockIdx.z;
    const int lm = l & 15, lq = l >> 4;

    int arow[2], brow[2];
#pragma unroll
    for (int i = 0; i < 2; ++i) {
        int rr = w * 32 + i * 16 + (l >> 2);
        int c  = (l & 3) ^ ((rr >> 1) & 3);
        arow[i] = (nn * 512 + q0 + rr) * 256 + c * 8;
        brow[i] = (nn * 512 + k0 + rr) * 256 + c * 8;
    }
    const int lds0 = w * 2048, lds1 = w * 2048 + 1024;

    int aoff[4], boff[4];
#pragma unroll
    for (int mi = 0; mi < 4; ++mi) {
        int row = (w & 1) * 64 + mi * 16 + lm;
        aoff[mi] = row * 32 + (lq ^ ((row >> 1) & 3)) * 8;
    }
#pragma unroll
    for (int ni = 0; ni < 4; ++ni) {
        int row = (w >> 1) * 64 + ni * 16 + lm;
        boff[ni] = row * 32 + (lq ^ ((row >> 1) & 3)) * 8;
    }

    f32x4 acc[4][4];
#pragma unroll
    for (int mi = 0; mi < 4; ++mi)
#pragma unroll
        for (int ni = 0; ni < 4; ++ni) acc[mi][ni] = (f32x4){0.f, 0.f, 0.f, 0.f};

    for (int t0 = 0; t0 < 256; t0 += 32) {
        gl_lds16(Qh + arow[0] + t0, (char*)Ah + lds0);
        gl_lds16(Qh + arow[1] + t0, (char*)Ah + lds1);
        gl_lds16(Ql + arow[0] + t0, (char*)Al + lds0);
        gl_lds16(Ql + arow[1] + t0, (char*)Al + lds1);
        gl_lds16(Kh + brow[0] + t0, (char*)Bh + lds0);
        gl_lds16(Kh + brow[1] + t0, (char*)Bh + lds1);
        gl_lds16(Kl + brow[0] + t0, (char*)Bl + lds0);
        gl_lds16(Kl + brow[1] + t0, (char*)Bl + lds1);
        __syncthreads();
        short8 ah[4], bh[4];
#pragma unroll
        for (int mi = 0; mi < 4; ++mi) ah[mi] = *(const short8*)&Ah[aoff[mi]];
#pragma unroll
        for (int ni = 0; ni < 4; ++ni) bh[ni] = *(const short8*)&Bh[boff[ni]];
#pragma unroll
        for (int mi = 0; mi < 4; ++mi)
#pragma unroll
            for (int ni = 0; ni < 4; ++ni)
                acc[mi][ni] = MFMA16(ah[mi], bh[ni], acc[mi][ni]);
        {
            short8 alv[4], blv[4];
#pragma unroll
            for (int mi = 0; mi < 4; ++mi) alv[mi] = *(const short8*)&Al[aoff[mi]];
#pragma unroll
            for (int mi = 0; mi < 4; ++mi)
#pragma unroll
                for (int ni = 0; ni < 4; ++ni)
                    acc[mi][ni] = MFMA16(alv[mi], bh[ni], acc[mi][ni]);
#pragma unroll
            for (int ni = 0; ni < 4; ++ni) blv[ni] = *(const short8*)&Bl[boff[ni]];
#pragma unroll
            for (int mi = 0; mi < 4; ++mi)
#pragma unroll
                for (int ni = 0; ni < 4; ++ni)
                    acc[mi][ni] = MFMA16(ah[mi], blv[ni], acc[mi][ni]);
        }
        __syncthreads();
    }

    float* C = Sc + nn * 262144;
#pragma unroll
    for (int mi = 0; mi < 4; ++mi) {
        int qb = q0 + (w & 1) * 64 + lq * 4 + mi * 16;
#pragma unroll
        for (int ni = 0; ni < 4; ++ni) {
            int col = k0 + (w >> 1) * 64 + ni * 16 + lm;
#pragma unroll
            for (int r = 0; r < 4; ++r)
                C[(qb + r) * 512 + col] = acc[mi][ni][r];
        }
    }
}

// ---- softmax rows of 512 (+ zero Sp halo buffer while we're here) ----
__global__ __launch_bounds__(256) void k_softmax(float* __restrict__ Sc,
                                                 unsigned short* __restrict__ Ph,
                                                 unsigned int* __restrict__ Spz) {
    unsigned zi = blockIdx.x * 256 + threadIdx.x;
    if (zi < 2641920u) Spz[zi] = 0u;           // 5,283,840 shorts of Sp
    __shared__ float red[8];
    float* p = Sc + (size_t)blockIdx.x * 512;
    unsigned short* ph = Ph + (size_t)blockIdx.x * 512;
    const int tid = threadIdx.x;
    float x0 = p[tid], x1 = p[tid + 256];
    float m = fmaxf(x0, x1);
#pragma unroll
    for (int off = 32; off; off >>= 1) m = fmaxf(m, __shfl_xor(m, off));
    if ((tid & 63) == 0) red[tid >> 6] = m;
    __syncthreads();
    m = fmaxf(fmaxf(red[0], red[1]), fmaxf(red[2], red[3]));
    float e0 = __expf(x0 - m), e1 = __expf(x1 - m);
    float s = e0 + e1;
#pragma unroll
    for (int off = 32; off; off >>= 1) s += __shfl_xor(s, off);
    if ((tid & 63) == 0) red[4 + (tid >> 6)] = s;
    __syncthreads();
    s = red[4] + red[5] + red[6] + red[7];
    float inv = 1.0f / s;
    float p0 = e0 * inv, p1 = e1 * inv;
    p[tid] = p0;
    p[tid + 256] = p1;
    ph[tid] = f2bf(p0);
    ph[tid + 256] = f2bf(p1);
}

// ---- PV: P @ V, 16x16 bf16 MFMA; epilogue scatters into padded Sp ----
__global__ __launch_bounds__(256) void k_pv_mfma(
        const unsigned short* __restrict__ Ph, const unsigned short* __restrict__ Vt,
        unsigned short* __restrict__ Sp) {
    __shared__ __align__(16) short Ah[4096], Bh[2048];
    const int tid = threadIdx.x;
    const int w = tid >> 6, l = tid & 63;
    const int q0 = blockIdx.x * 128, t0 = blockIdx.y * 64, nn = blockIdx.z;
    const int lm = l & 15, lq = l >> 4;

    int arow[2], brow;
#pragma unroll
    for (int i = 0; i < 2; ++i) {
        int rr = w * 32 + i * 16 + (l >> 2);
        int c  = (l & 3) ^ ((rr >> 1) & 3);
        arow[i] = (nn * 512 + q0 + rr) * 512 + c * 8;
    }
    {
        int rr = w * 16 + (l >> 2);
        int c  = (l & 3) ^ ((rr >> 1) & 3);
        brow = (nn * 256 + t0 + rr) * 512 + c * 8;
    }
    const int ldsA0 = w * 2048, ldsA1 = w * 2048 + 1024, ldsB = w * 1024;

    int aoff[4], boff[2];
#pragma unroll
    for (int mi = 0; mi < 4; ++mi) {
        int row = (w & 1) * 64 + mi * 16 + lm;
        aoff[mi] = row * 32 + (lq ^ ((row >> 1) & 3)) * 8;
    }
#pragma unroll
    for (int ni = 0; ni < 2; ++ni) {
        int row = (w >> 1) * 32 + ni * 16 + lm;
        boff[ni] = row * 32 + (lq ^ ((row >> 1) & 3)) * 8;
    }

    f32x4 acc[4][2];
#pragma unroll
    for (int mi = 0; mi < 4; ++mi)
#pragma unroll
        for (int ni = 0; ni < 2; ++ni) acc[mi][ni] = (f32x4){0.f, 0.f, 0.f, 0.f};

    for (int kc = 0; kc < 512; kc += 32) {
        gl_lds16(Ph + arow[0] + kc, (char*)Ah + ldsA0);
        gl_lds16(Ph + arow[1] + kc, (char*)Ah + ldsA1);
        gl_lds16(Vt + brow + kc, (char*)Bh + ldsB);
        __syncthreads();
        short8 a[4], b[2];
#pragma unroll
        for (int mi = 0; mi < 4; ++mi) a[mi] = *(const short8*)&Ah[aoff[mi]];
#pragma unroll
        for (int ni = 0; ni < 2; ++ni) b[ni] = *(const short8*)&Bh[boff[ni]];
#pragma unroll
        for (int mi = 0; mi < 4; ++mi)
#pragma unroll
            for (int ni = 0; ni < 2; ++ni)
                acc[mi][ni] = MFMA16(a[mi], b[ni], acc[mi][ni]);
        __syncthreads();
    }

    // scatter into Sp[b2][yy][xx][d2]:  b2=nn>>3, s2=nn&7,
    //   ww=(qp>>4)*8+((qp>>1)&7), d2=(qp&1)*256+(t&31)*8+(t>>5)
    const int b2 = nn >> 3, s2 = nn & 7;
#pragma unroll
    for (int mi = 0; mi < 4; ++mi) {
        int qb = q0 + (w & 1) * 64 + lq * 4 + mi * 16;
#pragma unroll
        for (int ni = 0; ni < 2; ++ni) {
            int tc = t0 + (w >> 1) * 32 + ni * 16 + lm;
            int d2base = (tc & 31) * 8 + (tc >> 5);
#pragma unroll
            for (int r = 0; r < 4; ++r) {
                int qp = qb + r;
                int ww = (qp >> 4) * 8 + ((qp >> 1) & 7);
                int d2 = (qp & 1) * 256 + d2base;
                Sp[((b2 * 10 + s2 + 1) * 258 + ww + 1) * 512 + d2] =
                    f2bf(acc[mi][ni][r]);
            }
        }
    }
}

// ---- output conv (16x16), BM=128 BN=64 -> Y NCHW fp32 ----
__global__ __launch_bounds__(256) void k_conv_o_mfma(
        const unsigned short* __restrict__ Sp, const unsigned short* __restrict__ Wh,
        const float* __restrict__ bias, float* __restrict__ Y) {
    __shared__ __align__(16) short Ah[4096], Bh[2048];
    const int tid = threadIdx.x;
    const int w = tid >> 6, l = tid & 63;
    const int n   = blockIdx.x >> 4;
    const int yy  = (blockIdx.x >> 1) & 7;
    const int x0  = (blockIdx.x & 1) * 128;
    const int co0 = blockIdx.y * 64;
    const int lm = l & 15, lq = l >> 4;

    int arow[2], brow;
#pragma unroll
    for (int i = 0; i < 2; ++i) {
        int rr = w * 32 + i * 16 + (l >> 2);
        int c  = (l & 3) ^ ((rr >> 1) & 3);
        arow[i] = ((n * 10 + yy + 1) * 258 + (x0 + rr + 1)) * 512 + c * 8;
    }
    {
        int rr = w * 16 + (l >> 2);
        int c  = (l & 3) ^ ((rr >> 1) & 3);
        brow = (co0 + rr) * 4608 + c * 8;
    }
    const int ldsA0 = w * 2048, ldsA1 = w * 2048 + 1024, ldsB = w * 1024;

    int aoff[4], boff[2];
#pragma unroll
    for (int mi = 0; mi < 4; ++mi) {
        int row = (w & 1) * 64 + mi * 16 + lm;
        aoff[mi] = row * 32 + (lq ^ ((row >> 1) & 3)) * 8;
    }
#pragma unroll
    for (int ni = 0; ni < 2; ++ni) {
        int row = (w >> 1) * 32 + ni * 16 + lm;
        boff[ni] = row * 32 + (lq ^ ((row >> 1) & 3)) * 8;
    }

    f32x4 acc[4][2];
#pragma unroll
    for (int ni = 0; ni < 2; ++ni) {
        float b = bias[co0 + (w >> 1) * 32 + ni * 16 + lm];
#pragma unroll
        for (int mi = 0; mi < 4; ++mi) acc[mi][ni] = (f32x4){b, b, b, b};
    }

    for (int tap = 0; tap < 9; ++tap) {
        const int tapoff = ((tap / 3 - 1) * 258 + (tap % 3 - 1)) * 512;
        const int wb = tap * 512;
        for (int ci0 = 0; ci0 < 512; ci0 += 32) {
            gl_lds16(Sp + arow[0] + tapoff + ci0, (char*)Ah + ldsA0);
            gl_lds16(Sp + arow[1] + tapoff + ci0, (char*)Ah + ldsA1);
            gl_lds16(Wh + brow + wb + ci0, (char*)Bh + ldsB);
            __syncthreads();
            short8 a[4], b[2];
#pragma unroll
            for (int mi = 0; mi < 4; ++mi) a[mi] = *(const short8*)&Ah[aoff[mi]];
#pragma unroll
            for (int ni = 0; ni < 2; ++ni) b[ni] = *(const short8*)&Bh[boff[ni]];
#pragma unroll
            for (int mi = 0; mi < 4; ++mi)
#pragma unroll
                for (int ni = 0; ni < 2; ++ni)
                    acc[mi][ni] = MFMA16(a[mi], b[ni], acc[mi][ni]);
            __syncthreads();
        }
    }

#pragma unroll
    for (int mi = 0; mi < 4; ++mi) {
        int px = x0 + (w & 1) * 64 + lq * 4 + mi * 16;
#pragma unroll
        for (int ni = 0; ni < 2; ++ni) {
            int co = co0 + (w >> 1) * 32 + ni * 16 + lm;
            *(f32x4*)&Y[n * 1048576 + co * 2048 + yy * 256 + px] = acc[mi][ni];
        }
    }
}

// ---------------------------------------------------------------------------
extern "C" void kernel_launch(void* const* d_in, const int* in_sizes, int n_in,
                              void* d_out, int out_size, void* d_ws, size_t ws_size,
                              hipStream_t stream) {
    const float* q  = (const float*)d_in[0];
    const float* k  = (const float*)d_in[1];
    const float* v  = (const float*)d_in[2];
    const float* Wq = (const float*)d_in[3];
    const float* bq = (const float*)d_in[4];
    const float* Wk = (const float*)d_in[5];
    const float* bk = (const float*)d_in[6];
    const float* Wv = (const float*)d_in[7];
    const float* bv = (const float*)d_in[8];
    const float* Wo = (const float*)d_in[9];
    const float* bo = (const float*)d_in[10];

    // ---- workspace layout (shorts); total 40,697,856 shorts = 81.4 MB ----
    unsigned short* W0  = (unsigned short*)d_ws;
    unsigned short* Wqh = W0;                   // 2359296 each
    unsigned short* Wql = W0 + 2359296;
    unsigned short* Wkh = W0 + 4718592;
    unsigned short* Wkl = W0 + 7077888;
    unsigned short* Wvh = W0 + 9437184;
    unsigned short* Woh = W0 + 11796480;
    unsigned short* Xvh = W0 + 14155776;        // 5570560
    unsigned short* Qh  = W0 + 19726336;        // 4194304 each
    unsigned short* Ql  = W0 + 23920640;
    unsigned short* Kh  = W0 + 28114944;
    unsigned short* Kl  = W0 + 32309248;
    unsigned short* Vt  = W0 + 36503552;
    // reuses (lifetimes): Ph over Wqh..Wkl-part (dead after conv; Woh intact);
    //                     Sp over Ql+Kh (dead after scores)
    unsigned short* Ph = W0;                    // 8388608 shorts
    unsigned short* Sp = W0 + 23920640;         // 5283840 shorts

    // ---- d_out scratch before final writes ----
    float* y_out = (float*)d_out;               // 4194304 floats (written last)
    float* attn  = y_out + 4194304;             // 8388608 floats (written by scores)
    unsigned short* Xqh = (unsigned short*)d_out;
    unsigned short* Xql = (unsigned short*)attn;
    unsigned short* Xkh = Xql + 5570560;
    unsigned short* Xkl = Xkh + 5570560;

    k_prep_all<<<102144, 256, 0, stream>>>(q, k, v, Wq, Wk, Wv, Wo,
                                           Wqh, Wql, Wkh, Wkl, Wvh, Woh,
                                           Xqh, Xql, Xkh, Xkl, Xvh);
    k_conv_qkv_all<<<dim3(64, 4, 3), 256, 0, stream>>>(
        Xqh, Xql, Xkh, Xkl, Xvh, Wqh, Wql, Wkh, Wkl, Wvh,
        bq, bk, bv, Qh, Ql, Kh, Kl, Vt);
    k_scores_mfma<<<dim3(4, 4, 32), 256, 0, stream>>>(Qh, Ql, Kh, Kl, attn);
    k_softmax<<<16384, 256, 0, stream>>>(attn, Ph, (unsigned int*)Sp);
    k_pv_mfma<<<dim3(4, 4, 32), 256, 0, stream>>>(Ph, Vt, Sp);
    k_conv_o_mfma<<<dim3(64, 8), 256, 0, stream>>>(Sp, Woh, bo, y_out);
}